// Round 15
// baseline (118.959 us; speedup 1.0000x reference)
//
#include <hip/hip_runtime.h>
#include <hip/hip_bf16.h>
#include <math.h>

#define N_TOT 8192
#define HALF_N 4096
#define D_DIM 512
#define BM 128
#define BK 128         // fp8 bytes per K-chunk; 4 K-iterations, 128B LDS rows
#define NKIT (D_DIM / BK)
#define NTILES 2080    // 64*65/2 upper-triangle 128x128 tiles

typedef float f32x4_t __attribute__((ext_vector_type(4)));
typedef long long i64x2 __attribute__((ext_vector_type(2)));

typedef __attribute__((address_space(1))) unsigned int g_u32;
typedef __attribute__((address_space(3))) unsigned int l_u32;

// Kernel 1: L2-normalize rows of [p1;p2] -> fp8 e4m3 Z in k-PERMUTED layout
// (validated R9/R11/R12): within each 64B k-block, source byte k (q=(k>>3)&3,
// h=(k>>5)&1) stored at q*16 + h*8 + (k&7). Both GEMM operands use the same
// bijection, so dot products are unaffected; a lane's two 8B MFMA k-pieces
// are one contiguous 16B chunk -> single ds_read_b128 fragments.
__global__ __launch_bounds__(256) void k_normalize(
    const float* __restrict__ p1, const float* __restrict__ p2,
    unsigned char* __restrict__ zf8, float* __restrict__ rowsum,
    float* __restrict__ out)
{
    const int w = threadIdx.x >> 6;
    const int lane = threadIdx.x & 63;
    const int row = blockIdx.x * 4 + w;

    if (threadIdx.x < 4) rowsum[blockIdx.x * 4 + threadIdx.x] = 0.0f;
    if (blockIdx.x == 0 && threadIdx.x == 0) out[0] = 0.0f;

    const float* src = (row < HALF_N) ? p1 + (size_t)row * D_DIM
                                      : p2 + (size_t)(row - HALF_N) * D_DIM;
    float4 a = *(const float4*)(src + lane * 4);
    float4 b = *(const float4*)(src + 256 + lane * 4);
    float s = a.x*a.x + a.y*a.y + a.z*a.z + a.w*a.w
            + b.x*b.x + b.y*b.y + b.z*b.z + b.w*b.w;
    #pragma unroll
    for (int m = 1; m < 64; m <<= 1) s += __shfl_xor(s, m, 64);
    float inv = 1.0f / fmaxf(sqrtf(s), 1e-8f);

    int pk0 = __builtin_amdgcn_cvt_pk_fp8_f32(a.x * inv, a.y * inv, 0, false);
    pk0     = __builtin_amdgcn_cvt_pk_fp8_f32(a.z * inv, a.w * inv, pk0, true);
    int pk1 = __builtin_amdgcn_cvt_pk_fp8_f32(b.x * inv, b.y * inv, 0, false);
    pk1     = __builtin_amdgcn_cvt_pk_fp8_f32(b.z * inv, b.w * inv, pk1, true);

    unsigned char* dst = zf8 + (size_t)row * D_DIM;
    const int o0 = lane * 4;
    const int o1 = 256 + lane * 4;
    const int d0 = (o0 & ~63) + ((o0 >> 3) & 3) * 16 + ((o0 >> 5) & 1) * 8 + (o0 & 4);
    const int d1 = (o1 & ~63) + ((o1 >> 3) & 3) * 16 + ((o1 >> 5) & 1) * 8 + (o1 & 4);
    *(int*)(dst + d0) = pk0;
    *(int*)(dst + d1) = pk1;
}

// Kernel 2: one 128x128 upper-triangle tile per block, 512 threads (8 waves),
// BK=128: 32 MFMA/barrier/wave (R11's best) at only 4 barriers/tile (vs 8).
// Wave w: rows [(w>>1)*32,+32) x cols [(w&1)*64,+64) -> 32 AGPR acc (R14-
// verified epilogue). Double-buffered LDS (64KB, 2 blocks/CU), __syncthreads
// only (no manual waitcnt: R13 outlier; no __threadfence: R5/R6). 128B LDS
// rows with XOR chunk swizzle: slot cc of row r holds source chunk cc^(r&7).
__global__ __launch_bounds__(512, 4) void k_gemm(
    const unsigned char* __restrict__ zf8,
    float* __restrict__ rowsum, float* __restrict__ pos)
{
    __shared__ __align__(16) unsigned char As[2][BM * BK];  // 2 x 16 KB
    __shared__ __align__(16) unsigned char Bs[2][BM * BK];  // 2 x 16 KB

    const int tid = threadIdx.x;
    const int lane = tid & 63;
    const int w = tid >> 6;          // 0..7
    const int wr = w >> 1;           // 0..3: 32-row strip
    const int wc = w & 1;            // 0..1: 64-col half
    const int q = lane >> 4, l15 = lane & 15;

    // triangular block mapping: t -> (bx >= by)
    const int t = blockIdx.x;
    int bi = (int)((sqrtf(8.0f * (float)t + 1.0f) - 1.0f) * 0.5f);
    while ((bi + 1) * (bi + 2) / 2 <= t) ++bi;
    while (bi * (bi + 1) / 2 > t) --bi;
    const int bx = bi;                       // col tile (larger)
    const int by = t - bi * (bi + 1) / 2;    // row tile
    const bool isDiag = (bx == by);
    const bool hasPos = (bx - by == 32);
    const int rowBase = by * BM;
    const int colBase = bx * BM;

    // staging: per panel per iter = 1024 chunks of 16B; thread t handles
    // chunk t and t+512. row = ci>>3 (128B rows), cc = ci&7, source chunk
    // XOR-swizzled gc = cc ^ (row&7). Dest lane-contiguous (tid*16).
    const int sr0 = tid >> 3,        scc0 = tid & 7;
    const int sr1 = (tid + 512) >> 3;  // = 64 + sr0
    const int sgc0 = scc0 ^ (sr0 & 7);
    const int sgc1 = scc0 ^ (sr1 & 7); // sr1&7 == sr0&7, kept explicit

    const unsigned char* gA0 = zf8 + (size_t)(rowBase + sr0) * D_DIM + sgc0 * 16;
    const unsigned char* gA1 = zf8 + (size_t)(rowBase + sr1) * D_DIM + sgc1 * 16;
    const unsigned char* gB0 = zf8 + (size_t)(colBase + sr0) * D_DIM + sgc0 * 16;
    const unsigned char* gB1 = zf8 + (size_t)(colBase + sr1) * D_DIM + sgc1 * 16;

    f32x4_t acc[2][4] = {};

    __builtin_amdgcn_global_load_lds((const g_u32*)gA0, (l_u32*)&As[0][tid * 16], 16, 0, 0);
    __builtin_amdgcn_global_load_lds((const g_u32*)gA1, (l_u32*)&As[0][(tid + 512) * 16], 16, 0, 0);
    __builtin_amdgcn_global_load_lds((const g_u32*)gB0, (l_u32*)&Bs[0][tid * 16], 16, 0, 0);
    __builtin_amdgcn_global_load_lds((const g_u32*)gB1, (l_u32*)&Bs[0][(tid + 512) * 16], 16, 0, 0);

    #pragma unroll
    for (int it = 0; it < NKIT; it++) {
        const int cur = it & 1;
        __syncthreads();  // buf[cur] ready; buf[1-cur] free

        if (it + 1 < NKIT) {
            const int kb = (it + 1) * BK;
            const int nxt = 1 - cur;
            __builtin_amdgcn_global_load_lds((const g_u32*)(gA0 + kb), (l_u32*)&As[nxt][tid * 16], 16, 0, 0);
            __builtin_amdgcn_global_load_lds((const g_u32*)(gA1 + kb), (l_u32*)&As[nxt][(tid + 512) * 16], 16, 0, 0);
            __builtin_amdgcn_global_load_lds((const g_u32*)(gB0 + kb), (l_u32*)&Bs[nxt][tid * 16], 16, 0, 0);
            __builtin_amdgcn_global_load_lds((const g_u32*)(gB1 + kb), (l_u32*)&Bs[nxt][(tid + 512) * 16], 16, 0, 0);
        }

        // fragments: source chunk (kb2*4 + q) of row r at slot (kb2*4+q)^(r&7)
        #pragma unroll
        for (int kb2 = 0; kb2 < 2; kb2++) {
            i64x2 aF[2], bF[4];
            #pragma unroll
            for (int i = 0; i < 2; i++) {
                const int ra = wr * 32 + i * 16 + l15;
                aF[i] = *(const i64x2*)&As[cur][ra * BK + ((kb2 * 4 + q) ^ (ra & 7)) * 16];
            }
            #pragma unroll
            for (int j = 0; j < 4; j++) {
                const int rb = wc * 64 + j * 16 + l15;
                bF[j] = *(const i64x2*)&Bs[cur][rb * BK + ((kb2 * 4 + q) ^ (rb & 7)) * 16];
            }
            #pragma unroll
            for (int h = 0; h < 2; h++)
                #pragma unroll
                for (int i = 0; i < 2; i++)
                    #pragma unroll
                    for (int j = 0; j < 4; j++)
                        acc[i][j] = __builtin_amdgcn_mfma_f32_16x16x32_fp8_fp8(
                            aF[i][h], bF[j][h], acc[i][j], 0, 0, 0);
        }
    }

    // Epilogue (R14-verified). C/D: col = lane&15, row = (lane>>4)*4 + reg.
    float colacc[4] = {0.f, 0.f, 0.f, 0.f};
    #pragma unroll
    for (int i = 0; i < 2; i++) {
        #pragma unroll
        for (int r = 0; r < 4; r++) {
            const int row = rowBase + wr * 32 + i * 16 + q * 4 + r;
            float rs = 0.0f;
            #pragma unroll
            for (int j = 0; j < 4; j++) {
                const int col = colBase + wc * 64 + j * 16 + l15;
                const float c = acc[i][j][r];
                float e = __expf(c);
                if (isDiag && col == row) e = 0.0f;
                rs += e;
                colacc[j] += e;
                if (hasPos && col == row + HALF_N) { pos[row] = c; pos[col] = c; }
            }
            rs += __shfl_xor(rs, 1); rs += __shfl_xor(rs, 2);
            rs += __shfl_xor(rs, 4); rs += __shfl_xor(rs, 8);
            if (l15 == 0) atomicAdd(&rowsum[row], rs);
        }
    }
    if (!isDiag) {
        #pragma unroll
        for (int j = 0; j < 4; j++) {
            float cs = colacc[j];
            cs += __shfl_xor(cs, 16);
            cs += __shfl_xor(cs, 32);
            if (q == 0) atomicAdd(&rowsum[colBase + wc * 64 + j * 16 + l15], cs);
        }
    }
}

// Kernel 3: mean over rows of (log(rowsum) - pos) -> scalar (out pre-zeroed).
__global__ __launch_bounds__(256) void k_finalize(
    const float* __restrict__ rowsum, const float* __restrict__ pos,
    float* __restrict__ out)
{
    const int t = threadIdx.x;
    const int i = blockIdx.x * 256 + t;
    float s = logf(rowsum[i]) - pos[i];
    #pragma unroll
    for (int m = 1; m < 64; m <<= 1) s += __shfl_xor(s, m, 64);
    __shared__ float red[4];
    if ((t & 63) == 0) red[t >> 6] = s;
    __syncthreads();
    if (t == 0)
        atomicAdd(out, (red[0] + red[1] + red[2] + red[3]) * (1.0f / (float)N_TOT));
}

extern "C" void kernel_launch(void* const* d_in, const int* in_sizes, int n_in,
                              void* d_out, int out_size, void* d_ws, size_t ws_size,
                              hipStream_t stream) {
    const float* p1 = (const float*)d_in[0];
    const float* p2 = (const float*)d_in[1];

    unsigned char* zf8 = (unsigned char*)d_ws;                          // 4 MB
    float* rowsum = (float*)((char*)d_ws + (size_t)N_TOT * D_DIM);      // 32 KB
    float* pos    = rowsum + N_TOT;                                     // 32 KB
    float* outp   = (float*)d_out;

    k_normalize<<<N_TOT / 4, 256, 0, stream>>>(p1, p2, zf8, rowsum, outp);
    k_gemm<<<NTILES, 512, 0, stream>>>(zf8, rowsum, pos);
    k_finalize<<<N_TOT / 256, 256, 0, stream>>>(rowsum, pos, outp);
}

// Round 16
// 106.238 us; speedup vs baseline: 1.1197x; 1.1197x over previous
//
#include <hip/hip_runtime.h>
#include <hip/hip_bf16.h>
#include <math.h>

#define N_TOT 8192
#define HALF_N 4096
#define D_DIM 512
#define BM 128
#define BK 64          // fp8 bytes per K-chunk; 8 K-iterations, 64B LDS rows
#define NKIT (D_DIM / BK)
#define NTILES 2080    // 64*65/2 upper-triangle 128x128 tiles

// s_waitcnt imm: vmcnt[3:0] | expcnt<<4 | lgkmcnt<<8 (expcnt/lgkmcnt = max -> unconstrained)
#define WAIT_VM4 0xF74
#define WAIT_VM0 0xF70

typedef float f32x4_t __attribute__((ext_vector_type(4)));
typedef long long i64x2 __attribute__((ext_vector_type(2)));

typedef __attribute__((address_space(1))) unsigned int g_u32;
typedef __attribute__((address_space(3))) unsigned int l_u32;

// Kernel 1: L2-normalize rows of [p1;p2] -> fp8 e4m3 Z in k-PERMUTED layout
// (validated R9/R11/R12): within each 64B k-block, source byte k (q=(k>>3)&3,
// h=(k>>5)&1) stored at q*16 + h*8 + (k&7). Both GEMM operands use the same
// bijection, so dot products are unaffected; a lane's two 8B MFMA k-pieces
// are one contiguous 16B chunk -> single ds_read_b128, zero bank conflicts.
__global__ __launch_bounds__(256) void k_normalize(
    const float* __restrict__ p1, const float* __restrict__ p2,
    unsigned char* __restrict__ zf8, float* __restrict__ rowsum,
    float* __restrict__ out)
{
    const int w = threadIdx.x >> 6;
    const int lane = threadIdx.x & 63;
    const int row = blockIdx.x * 4 + w;

    if (threadIdx.x < 4) rowsum[blockIdx.x * 4 + threadIdx.x] = 0.0f;
    if (blockIdx.x == 0 && threadIdx.x == 0) out[0] = 0.0f;

    const float* src = (row < HALF_N) ? p1 + (size_t)row * D_DIM
                                      : p2 + (size_t)(row - HALF_N) * D_DIM;
    float4 a = *(const float4*)(src + lane * 4);
    float4 b = *(const float4*)(src + 256 + lane * 4);
    float s = a.x*a.x + a.y*a.y + a.z*a.z + a.w*a.w
            + b.x*b.x + b.y*b.y + b.z*b.z + b.w*b.w;
    #pragma unroll
    for (int m = 1; m < 64; m <<= 1) s += __shfl_xor(s, m, 64);
    float inv = 1.0f / fmaxf(sqrtf(s), 1e-8f);

    int pk0 = __builtin_amdgcn_cvt_pk_fp8_f32(a.x * inv, a.y * inv, 0, false);
    pk0     = __builtin_amdgcn_cvt_pk_fp8_f32(a.z * inv, a.w * inv, pk0, true);
    int pk1 = __builtin_amdgcn_cvt_pk_fp8_f32(b.x * inv, b.y * inv, 0, false);
    pk1     = __builtin_amdgcn_cvt_pk_fp8_f32(b.z * inv, b.w * inv, pk1, true);

    unsigned char* dst = zf8 + (size_t)row * D_DIM;
    const int o0 = lane * 4;
    const int o1 = 256 + lane * 4;
    const int d0 = (o0 & ~63) + ((o0 >> 3) & 3) * 16 + ((o0 >> 5) & 1) * 8 + (o0 & 4);
    const int d1 = (o1 & ~63) + ((o1 >> 3) & 3) * 16 + ((o1 >> 5) & 1) * 8 + (o1 & 4);
    *(int*)(dst + d0) = pk0;
    *(int*)(dst + d1) = pk1;
}

// Kernel 2 (R12 best-known config): upper-triangle tiles of sim = Z*Z^T via
// fp8 MFMA 16x16x32. TRIPLE-buffered LDS, prefetch distance 2, manual
// `s_waitcnt vmcnt(4)` + s_barrier: each barrier keeps the NEXT iteration's
// 4 loads in flight (waits only the 4 oldest = current buffer). WAW safe:
// prefetch for buf[(it+2)%3] is issued after the barrier ending all reads of
// it. k-permuted layout -> b128 fragments, 0 bank conflicts. No
// __threadfence (R5/R6 lesson: device fence = kernel-wide L2 inval storm).
__global__ __launch_bounds__(256, 4) void k_gemm(
    const unsigned char* __restrict__ zf8,
    float* __restrict__ rowsum, float* __restrict__ pos)
{
    __shared__ __align__(16) unsigned char As[3][BM * BK];  // 3 x 8 KB
    __shared__ __align__(16) unsigned char Bs[3][BM * BK];  // 3 x 8 KB

    const int tid = threadIdx.x;
    const int lane = tid & 63;
    const int w = tid >> 6;
    const int wr = w >> 1, wc = w & 1;
    const int q = lane >> 4, l15 = lane & 15;

    // triangular block mapping: t -> (bx >= by)
    const int t = blockIdx.x;
    int bi = (int)((sqrtf(8.0f * (float)t + 1.0f) - 1.0f) * 0.5f);
    while ((bi + 1) * (bi + 2) / 2 <= t) ++bi;
    while (bi * (bi + 1) / 2 > t) --bi;
    const int bx = bi;                       // col tile (larger)
    const int by = t - bi * (bi + 1) / 2;    // row tile
    const bool isDiag = (bx == by);
    const bool hasPos = (bx - by == 32);
    const int rowBase = by * BM;
    const int colBase = bx * BM;

    // staging (R8/R11-proven): 16B chunks, dest chunk = tid / 256+tid,
    // LDS slot cc of row r holds source chunk cc ^ ((r>>1)&3).
    const int ci0 = tid;
    const int ci1 = 256 + tid;
    const int r0 = ci0 >> 2, cc0 = ci0 & 3;
    const int r1 = ci1 >> 2, cc1 = ci1 & 3;
    const int gc0 = cc0 ^ ((r0 >> 1) & 3);
    const int gc1 = cc1 ^ ((r1 >> 1) & 3);

    const unsigned char* gA0 = zf8 + (size_t)(rowBase + r0) * D_DIM + gc0 * 16;
    const unsigned char* gA1 = zf8 + (size_t)(rowBase + r1) * D_DIM + gc1 * 16;
    const unsigned char* gB0 = zf8 + (size_t)(colBase + r0) * D_DIM + gc0 * 16;
    const unsigned char* gB1 = zf8 + (size_t)(colBase + r1) * D_DIM + gc1 * 16;

    auto stage = [&](int buf, int kblk) {
        const int kb = kblk * BK;
        __builtin_amdgcn_global_load_lds((const g_u32*)(gA0 + kb), (l_u32*)&As[buf][ci0 * 16], 16, 0, 0);
        __builtin_amdgcn_global_load_lds((const g_u32*)(gA1 + kb), (l_u32*)&As[buf][ci1 * 16], 16, 0, 0);
        __builtin_amdgcn_global_load_lds((const g_u32*)(gB0 + kb), (l_u32*)&Bs[buf][ci0 * 16], 16, 0, 0);
        __builtin_amdgcn_global_load_lds((const g_u32*)(gB1 + kb), (l_u32*)&Bs[buf][ci1 * 16], 16, 0, 0);
    };

    f32x4_t acc[4][4] = {};

    stage(0, 0);   // 4 vm ops (oldest)
    stage(1, 1);   // 4 vm ops

    #pragma unroll
    for (int it = 0; it < NKIT; it++) {
        const int cur = it % 3;
        // wait ONLY the 4 oldest loads (= buf[cur]); keep next iter's 4 in flight
        if (it + 1 < NKIT) __builtin_amdgcn_s_waitcnt(WAIT_VM4);
        else               __builtin_amdgcn_s_waitcnt(WAIT_VM0);
        __builtin_amdgcn_s_barrier();

        if (it + 2 < NKIT) stage((it + 2) % 3, it + 2);

        i64x2 aF[4], bF[4];
        #pragma unroll
        for (int i = 0; i < 4; i++) {
            const int ra = wr * 64 + i * 16 + l15;
            const int rb = wc * 64 + i * 16 + l15;
            aF[i] = *(const i64x2*)&As[cur][ra * BK + (q ^ ((ra >> 1) & 3)) * 16];
            bF[i] = *(const i64x2*)&Bs[cur][rb * BK + (q ^ ((rb >> 1) & 3)) * 16];
        }
        #pragma unroll
        for (int h = 0; h < 2; h++)
            #pragma unroll
            for (int i = 0; i < 4; i++)
                #pragma unroll
                for (int j = 0; j < 4; j++)
                    acc[i][j] = __builtin_amdgcn_mfma_f32_16x16x32_fp8_fp8(
                        aF[i][h], bF[j][h], acc[i][j], 0, 0, 0);
    }

    // Epilogue. C/D layout (16x16 family): col = lane&15, row = (lane>>4)*4 + reg.
    float colacc[4] = {0.f, 0.f, 0.f, 0.f};
    #pragma unroll
    for (int i = 0; i < 4; i++) {
        #pragma unroll
        for (int r = 0; r < 4; r++) {
            const int row = rowBase + wr * 64 + i * 16 + q * 4 + r;
            float rs = 0.0f;
            #pragma unroll
            for (int j = 0; j < 4; j++) {
                const int col = colBase + wc * 64 + j * 16 + l15;
                const float c = acc[i][j][r];
                float e = __expf(c);
                if (isDiag && col == row) e = 0.0f;
                rs += e;
                colacc[j] += e;
                if (hasPos && col == row + HALF_N) { pos[row] = c; pos[col] = c; }
            }
            rs += __shfl_xor(rs, 1); rs += __shfl_xor(rs, 2);
            rs += __shfl_xor(rs, 4); rs += __shfl_xor(rs, 8);
            if (l15 == 0) atomicAdd(&rowsum[row], rs);
        }
    }
    if (!isDiag) {
        #pragma unroll
        for (int j = 0; j < 4; j++) {
            float cs = colacc[j];
            cs += __shfl_xor(cs, 16);
            cs += __shfl_xor(cs, 32);
            if (q == 0) atomicAdd(&rowsum[colBase + wc * 64 + j * 16 + l15], cs);
        }
    }
}

// Kernel 3: mean over rows of (log(rowsum) - pos) -> scalar (out pre-zeroed).
__global__ __launch_bounds__(256) void k_finalize(
    const float* __restrict__ rowsum, const float* __restrict__ pos,
    float* __restrict__ out)
{
    const int t = threadIdx.x;
    const int i = blockIdx.x * 256 + t;
    float s = logf(rowsum[i]) - pos[i];
    #pragma unroll
    for (int m = 1; m < 64; m <<= 1) s += __shfl_xor(s, m, 64);
    __shared__ float red[4];
    if ((t & 63) == 0) red[t >> 6] = s;
    __syncthreads();
    if (t == 0)
        atomicAdd(out, (red[0] + red[1] + red[2] + red[3]) * (1.0f / (float)N_TOT));
}

extern "C" void kernel_launch(void* const* d_in, const int* in_sizes, int n_in,
                              void* d_out, int out_size, void* d_ws, size_t ws_size,
                              hipStream_t stream) {
    const float* p1 = (const float*)d_in[0];
    const float* p2 = (const float*)d_in[1];

    unsigned char* zf8 = (unsigned char*)d_ws;                          // 4 MB
    float* rowsum = (float*)((char*)d_ws + (size_t)N_TOT * D_DIM);      // 32 KB
    float* pos    = rowsum + N_TOT;                                     // 32 KB
    float* outp   = (float*)d_out;

    k_normalize<<<N_TOT / 4, 256, 0, stream>>>(p1, p2, zf8, rowsum, outp);
    k_gemm<<<NTILES, 256, 0, stream>>>(zf8, rowsum, pos);
    k_finalize<<<N_TOT / 256, 256, 0, stream>>>(rowsum, pos, outp);
}